// Round 18
// baseline (143.823 us; speedup 1.0000x reference)
//
#include <hip/hip_runtime.h>
#include <hip/hip_fp16.h>

// Fused WeightedMAE + Patch-SSIM loss for (8,8,512,512) fp32 inputs.
// R18: software-pipelined 2-unit blocks (T14 issue-early/use-late).
// 4096 blocks x 256 thr; block = one (patch,channel), BOTH vertical halves.
// Unit1's 9 float4x3 global loads are issued into REGISTERS before barrier
// 1; latency hides under unit0's V/H compute (~4us >> ~1us). V-field LDS
// is reused across units without a barrier (wave-local rows; same-wave DS
// ops are in-order). Reduction barrier removed: per-wave direct atomics.
// Phase A0: load rows 0..36, pack (x,y) half2 -> xyt0, MAE rows r<32.
// Prefetch: issue rows 27..63 loads -> q_* regs.    [barrier 1]
// VH(u0): vertical conv (wave g owns 7 rows, lane=col, hfma2 packed) ->
//         wave-local horizontal conv + SSIM (63 units on 64 lanes).
// Phase A1: pack q_* -> xyt1, MAE rows r>=5.        [barrier 2]
// VH(u1), then shfl-reduce + per-wave slotted atomics.
// LDS = 2*9.25(xyt) + 6.96+6.96+3.59(V) = 36.9 KB -> 4 blocks/CU.
// waves_per_eu(4,4) pins the 128-VGPR budget (R13) for the 36 held regs.

#define C1c 1.0e-4f
#define C2c 9.0e-4f
#define NSLOT 64

struct alignas(16) xy4  { __half2 v[4]; };
struct alignas(8)  h2x2 { __half2 a, b; };

__device__ __forceinline__ float vh_unit(const __half2 (*xyt)[64],
                                         __half2 (*V01)[66],
                                         __half2 (*V23)[66],
                                         __half  (*V4)[68],
                                         const int lane, const int g) {
    // exp(-(j-5)^2/4.5)/sum, float32 pipeline (HW-validated); constant-folded
    const float WGT[11] = {0.00102838f, 0.00759874f, 0.03600076f, 0.10936068f,
                           0.21300564f, 0.26601172f, 0.21300564f, 0.10936068f,
                           0.03600076f, 0.00759874f, 0.00102838f};
    __half  WH[11];
    __half2 WH2[11];
#pragma unroll
    for (int j = 0; j < 11; ++j) {
        WH[j]  = __float2half_rn(WGT[j]);
        WH2[j] = __half2half2(WH[j]);
    }

    const int rb    = g * 7;                    // first owned out row
    const int nrows = (g == 3) ? 6 : 7;

    // ---- Phase V: vertical conv, wave-local rows ----
    {
        const int c     = lane;
        const int nread = (g == 3) ? 16 : 17;
        __half2 a01[7], a23[7];
        __half  a4[7];
#pragma unroll
        for (int i2 = 0; i2 < 7; ++i2) {
            a01[i2] = __half2half2(__float2half_rn(0.0f));
            a23[i2] = a01[i2];
            a4[i2]  = __float2half_rn(0.0f);
        }
#pragma unroll
        for (int ir = 0; ir < 17; ++ir) {
            if (ir < nread) {                   // wave-uniform
                const __half2 q   = xyt[rb + ir][c];
                const __half2 qq  = __hmul2(q, q);
                const __half  xyh = __hmul(__low2half(q), __high2half(q));
#pragma unroll
                for (int i2 = 0; i2 < 7; ++i2) {
                    const int j = ir - i2;
                    if (j >= 0 && j <= 10) {    // folds at compile time
                        if (i2 < 6 || g < 3) {  // wave-uniform (i2==6 only)
                            a01[i2] = __hfma2(WH2[j], q,  a01[i2]);
                            a23[i2] = __hfma2(WH2[j], qq, a23[i2]);
                            a4[i2]  = __hfma(WH[j], xyh, a4[i2]);
                        }
                    }
                }
            }
        }
#pragma unroll
        for (int i2 = 0; i2 < 7; ++i2) {
            if (i2 < 6 || g < 3) {
                V01[rb + i2][lane] = a01[i2];
                V23[rb + i2][lane] = a23[i2];
                V4 [rb + i2][lane] = a4[i2];
            }
        }
    }
    // NO barrier: same wave reads back only its own rows (DS ops in-order).

    // ---- Phase H: wave-local horizontal conv + SSIM ----
    float ssim_acc = 0.0f;
    if (lane < nrows * 9) {
        const int row_l = lane / 9;
        const int grp   = lane - row_l * 9;
        const int row   = rb + row_l;
        const int c0    = grp * 6;              // 0,6,..,48

        __half2 w01[16], w23[16];
        __half  w4[16];
        {
            const __half2* r01 = &V01[row][c0];
            const __half2* r23 = &V23[row][c0];
            const __half*  r4  = &V4 [row][c0];
#pragma unroll
            for (int t = 0; t < 8; ++t) {       // 8B-aligned b64 reads
                const h2x2 qa = *(const h2x2*)(r01 + 2 * t);
                w01[2*t] = qa.a; w01[2*t+1] = qa.b;
                const h2x2 qb = *(const h2x2*)(r23 + 2 * t);
                w23[2*t] = qb.a; w23[2*t+1] = qb.b;
                const __half2 qc = *(const __half2*)(r4 + 2 * t); // b32
                w4[2*t] = __low2half(qc); w4[2*t+1] = __high2half(qc);
            }
        }
#pragma unroll
        for (int k = 0; k < 6; ++k) {
            __half2 s01 = __half2half2(__float2half_rn(0.0f));
            __half2 s23 = s01;
            __half  s4  = __float2half_rn(0.0f);
#pragma unroll
            for (int j = 0; j < 11; ++j) {
                s01 = __hfma2(WH2[j], w01[k + j], s01);
                s23 = __hfma2(WH2[j], w23[k + j], s23);
                s4  = __hfma(WH[j], w4[k + j], s4);
            }
            const float mu1 = __low2float(s01);
            const float mu2 = __high2float(s01);
            const float sxx = __low2float(s23);
            const float syy = __high2float(s23);
            const float sxy = __half2float(s4);
            const float mu1sq = mu1 * mu1;
            const float mu2sq = mu2 * mu2;
            const float mu12  = mu1 * mu2;
            const float num = (2.0f * mu12 + C1c) * (2.0f * (sxy - mu12) + C2c);
            const float den = (mu1sq + mu2sq + C1c) *
                              ((sxx - mu1sq) + (syy - mu2sq) + C2c);
            ssim_acc = fmaf(num, __builtin_amdgcn_rcpf(den), ssim_acc);
        }
    }
    return ssim_acc;
}

__global__ __launch_bounds__(256)
__attribute__((amdgpu_waves_per_eu(4, 4)))
void fused_loss_kernel(const float* __restrict__ in,
                       const float* __restrict__ outp,
                       const float* __restrict__ tgt,
                       float* __restrict__ ws) {
    __shared__ alignas(16) __half2 xyt0[37][64];  // unit0: rows 0..36
    __shared__ alignas(16) __half2 xyt1[37][64];  // unit1: rows 27..63
    __shared__ alignas(16) __half2 V01[27][66];
    __shared__ alignas(16) __half2 V23[27][66];
    __shared__ alignas(16) __half  V4 [27][68];

    const int tid  = threadIdx.x;
    const int lane = tid & 63;
    const int g    = tid >> 6;

    // Address-streaming order (R17): XCD k = orig%8 owns image b=k;
    // within XCD, pw varies fastest -> contiguous 2KB row spans.
    const int orig = blockIdx.x;                 // 0..4095
    const int b    = orig & 7;
    const int i    = orig >> 3;                  // 0..511
    const int ch   = i >> 6;                     // 0..7
    const int ph   = (i >> 3) & 7;               // 0..7
    const int pw   = i & 7;                      // 0..7 (fastest)

    const size_t pc_base =
        ((size_t)(b * 8 + ch) * 512 + (size_t)(ph * 64)) * 512 +
        (size_t)(pw * 64);

    float mae_num = 0.0f, mae_den = 0.0f;

    // ---------------- Phase A0: rows 0..36 -> xyt0, MAE r<32 --------------
#pragma unroll
    for (int it = 0; it < 3; ++it) {
        const int slot = tid + it * 256;        // 0..591
        if (slot < 592) {
            const int r  = slot >> 4;           // 0..36
            const int c4 = (slot & 15) << 2;    // 0..60
            const size_t off = pc_base + (size_t)r * 512 + (size_t)c4;
            const float4 iv = *(const float4*)(in   + off);
            const float4 ov = *(const float4*)(outp + off);
            const float4 tv = *(const float4*)(tgt  + off);
            xy4 q;
            q.v[0] = __floats2half2_rn(iv.x + ov.x, tv.x);
            q.v[1] = __floats2half2_rn(iv.y + ov.y, tv.y);
            q.v[2] = __floats2half2_rn(iv.z + ov.z, tv.z);
            q.v[3] = __floats2half2_rn(iv.w + ov.w, tv.w);
            *(xy4*)&xyt0[r][c4] = q;
            if (r < 32) {
                float hp, w;
                hp = tv.x - iv.x; w = (fabsf(hp) > 0.0f) ? 1.0f : 0.0f;
                mae_den += w; mae_num = fmaf(w, fabsf(ov.x - hp), mae_num);
                hp = tv.y - iv.y; w = (fabsf(hp) > 0.0f) ? 1.0f : 0.0f;
                mae_den += w; mae_num = fmaf(w, fabsf(ov.y - hp), mae_num);
                hp = tv.z - iv.z; w = (fabsf(hp) > 0.0f) ? 1.0f : 0.0f;
                mae_den += w; mae_num = fmaf(w, fabsf(ov.z - hp), mae_num);
                hp = tv.w - iv.w; w = (fabsf(hp) > 0.0f) ? 1.0f : 0.0f;
                mae_den += w; mae_num = fmaf(w, fabsf(ov.w - hp), mae_num);
            }
        }
    }

    // ---------------- Prefetch unit1 (rows 27..63) into registers ---------
    float4 q_iv[3], q_ov[3], q_tv[3];           // constant-indexed -> regs
    {
        const size_t base1 = pc_base + (size_t)27 * 512;
#pragma unroll
        for (int it = 0; it < 3; ++it) {
            const int slot = tid + it * 256;
            if (slot < 592) {
                const size_t off = base1 + (size_t)(slot >> 4) * 512 +
                                   (size_t)((slot & 15) << 2);
                q_iv[it] = *(const float4*)(in   + off);
                q_ov[it] = *(const float4*)(outp + off);
                q_tv[it] = *(const float4*)(tgt  + off);
            }
        }
    }
    __syncthreads();                            // barrier 1: xyt0 ready

    // ---------------- VH(unit0) — prefetch loads in flight ----------------
    float ssim_acc = vh_unit(xyt0, V01, V23, V4, lane, g);

    // ---------------- Phase A1: pack prefetch -> xyt1, MAE r>=5 -----------
#pragma unroll
    for (int it = 0; it < 3; ++it) {
        const int slot = tid + it * 256;
        if (slot < 592) {
            const int r  = slot >> 4;
            const int c4 = (slot & 15) << 2;
            const float4 iv = q_iv[it];
            const float4 ov = q_ov[it];
            const float4 tv = q_tv[it];
            xy4 q;
            q.v[0] = __floats2half2_rn(iv.x + ov.x, tv.x);
            q.v[1] = __floats2half2_rn(iv.y + ov.y, tv.y);
            q.v[2] = __floats2half2_rn(iv.z + ov.z, tv.z);
            q.v[3] = __floats2half2_rn(iv.w + ov.w, tv.w);
            *(xy4*)&xyt1[r][c4] = q;
            if (r >= 5) {                       // global rows 32..63
                float hp, w;
                hp = tv.x - iv.x; w = (fabsf(hp) > 0.0f) ? 1.0f : 0.0f;
                mae_den += w; mae_num = fmaf(w, fabsf(ov.x - hp), mae_num);
                hp = tv.y - iv.y; w = (fabsf(hp) > 0.0f) ? 1.0f : 0.0f;
                mae_den += w; mae_num = fmaf(w, fabsf(ov.y - hp), mae_num);
                hp = tv.z - iv.z; w = (fabsf(hp) > 0.0f) ? 1.0f : 0.0f;
                mae_den += w; mae_num = fmaf(w, fabsf(ov.z - hp), mae_num);
                hp = tv.w - iv.w; w = (fabsf(hp) > 0.0f) ? 1.0f : 0.0f;
                mae_den += w; mae_num = fmaf(w, fabsf(ov.w - hp), mae_num);
            }
        }
    }
    __syncthreads();                            // barrier 2: xyt1 ready

    // ---------------- VH(unit1) ------------------------------------------
    ssim_acc += vh_unit(xyt1, V01, V23, V4, lane, g);

    // ---------------- Reduction: shfl -> per-wave atomics (no barrier) ----
    float v0 = mae_num, v1 = mae_den, v2 = ssim_acc;
#pragma unroll
    for (int off = 32; off >= 1; off >>= 1) {
        v0 += __shfl_down(v0, off);
        v1 += __shfl_down(v1, off);
        v2 += __shfl_down(v2, off);
    }
    if (lane == 0) {
        const int slot = (orig * 4 + g) & (NSLOT - 1);
        atomicAdd(&ws[slot * 3 + 0], v0);
        atomicAdd(&ws[slot * 3 + 1], v1);
        atomicAdd(&ws[slot * 3 + 2], v2);
    }
}

__global__ void finalize_kernel(const float* __restrict__ ws, float* __restrict__ out) {
    if (threadIdx.x == 0 && blockIdx.x == 0) {
        float r0 = 0.f, r1 = 0.f, r2 = 0.f;
        for (int i = 0; i < NSLOT; ++i) {
            r0 += ws[i * 3 + 0];
            r1 += ws[i * 3 + 1];
            r2 += ws[i * 3 + 2];
        }
        const float mae = r0 / (r1 + 1e-8f);
        const float ssim_mean = r2 * (1.0f / 11943936.0f);  // 4096 * 54 * 54
        out[0] = 0.5f * mae + 0.5f * (1.0f - ssim_mean);
    }
}

extern "C" void kernel_launch(void* const* d_in, const int* in_sizes, int n_in,
                              void* d_out, int out_size, void* d_ws, size_t ws_size,
                              hipStream_t stream) {
    const float* in   = (const float*)d_in[0];
    const float* outp = (const float*)d_in[1];
    const float* tgt  = (const float*)d_in[2];
    float* ws = (float*)d_ws;

    hipMemsetAsync(d_ws, 0, NSLOT * 3 * sizeof(float), stream);
    fused_loss_kernel<<<4096, 256, 0, stream>>>(in, outp, tgt, ws);
    finalize_kernel<<<1, 64, 0, stream>>>(ws, (float*)d_out);
}

// Round 19
// 71.732 us; speedup vs baseline: 2.0050x; 2.0050x over previous
//
#include <hip/hip_runtime.h>
#include <hip/hip_fp16.h>

// Fused WeightedMAE + Patch-SSIM loss for (8,8,512,512) fp32 inputs.
// R19 = R17 revert (best measured: 72.3us). R18's intra-block pipeline
// regressed (143us): halving block count + 37KB LDS + held prefetch regs
// destroyed the inter-block TLP that R9 proved is the primary lever.
// Structure: 8192 blocks (= 4096 patch-channel x 2 halves) x 256 threads,
// 26.8 KB LDS, single barrier, wave-local V->H, address-streaming order.
// Phase A: float4 loads of 37 rows, stage (x,y) packed half2, fused MAE.
// Phase V: vertical 11-tap conv {x,y,xx,yy,xy} packed fp16 (hfma2);
//          wave g owns 7 rows (g=3: 6), lane = col.
// Phase H (same wave, NO barrier: intra-wave LDS RAW lgkmcnt-ordered):
//          horizontal conv, 7 rows x 9 groups = 63 units on 64 lanes,
//          b64 window reads; SSIM with v_rcp_f32.

#define C1c 1.0e-4f
#define C2c 9.0e-4f
#define NSLOT 64

struct alignas(16) xy4  { __half2 v[4]; };
struct alignas(8)  h2x2 { __half2 a, b; };

__global__ __launch_bounds__(256)
void fused_loss_kernel(const float* __restrict__ in,
                       const float* __restrict__ outp,
                       const float* __restrict__ tgt,
                       float* __restrict__ ws) {
    __shared__ alignas(16) __half2 xyt[37][64];   // (x,y) per pixel
    __shared__ alignas(16) __half2 V01[27][66];   // (Gv*x, Gv*y), padded
    __shared__ alignas(16) __half2 V23[27][66];   // (Gv*xx, Gv*yy), padded
    __shared__ alignas(16) __half  V4 [27][68];   // Gv*xy
    __shared__ float red[4][3];

    // exp(-(j-5)^2/4.5)/sum, float32 pipeline (HW-validated)
    const float WGT[11] = {0.00102838f, 0.00759874f, 0.03600076f, 0.10936068f,
                           0.21300564f, 0.26601172f, 0.21300564f, 0.10936068f,
                           0.03600076f, 0.00759874f, 0.00102838f};
    __half  WH[11];
    __half2 WH2[11];
#pragma unroll
    for (int j = 0; j < 11; ++j) {       // constant-folded
        WH[j]  = __float2half_rn(WGT[j]);
        WH2[j] = __half2half2(WH[j]);
    }

    const int tid = threadIdx.x;

    // Address-streaming decomposition: XCD k (= orig%8) gets image b=k;
    // within XCD, i sweeps (ch, ph, half, pw) with pw fastest.
    const int orig = blockIdx.x;                 // 0..8191
    const int b    = orig & 7;                   // XCD-aligned batch image
    const int i    = orig >> 3;                  // 0..1023
    const int ch   = i >> 7;                     // 0..7
    const int ph   = (i >> 4) & 7;               // 0..7
    const int half = (i >> 3) & 1;               // 0..1
    const int pw   = i & 7;                      // 0..7  (fastest)
    const int r0   = half ? 27 : 0;

    // ---------------- Phase A: float4 load 37 rows, stage, fused MAE ------
    float mae_num = 0.0f, mae_den = 0.0f;
    const size_t img_base =
        ((size_t)(b * 8 + ch) * 512 + (size_t)(ph * 64 + r0)) * 512 +
        (size_t)(pw * 64);

#pragma unroll
    for (int it = 0; it < 3; ++it) {
        const int slot = tid + it * 256;        // 0..591
        if (slot < 592) {
            const int r  = slot >> 4;           // 0..36
            const int c4 = (slot & 15) << 2;    // 0..60
            const size_t off = img_base + (size_t)r * 512 + (size_t)c4;
            const float4 iv = *(const float4*)(in   + off);
            const float4 ov = *(const float4*)(outp + off);
            const float4 tv = *(const float4*)(tgt  + off);
            xy4 q;
            q.v[0] = __floats2half2_rn(iv.x + ov.x, tv.x);
            q.v[1] = __floats2half2_rn(iv.y + ov.y, tv.y);
            q.v[2] = __floats2half2_rn(iv.z + ov.z, tv.z);
            q.v[3] = __floats2half2_rn(iv.w + ov.w, tv.w);
            *(xy4*)&xyt[r][c4] = q;
            const bool own = half ? (r >= 5) : (r < 32);
            if (own) {
                float hp, w;
                hp = tv.x - iv.x; w = (fabsf(hp) > 0.0f) ? 1.0f : 0.0f;
                mae_den += w; mae_num = fmaf(w, fabsf(ov.x - hp), mae_num);
                hp = tv.y - iv.y; w = (fabsf(hp) > 0.0f) ? 1.0f : 0.0f;
                mae_den += w; mae_num = fmaf(w, fabsf(ov.y - hp), mae_num);
                hp = tv.z - iv.z; w = (fabsf(hp) > 0.0f) ? 1.0f : 0.0f;
                mae_den += w; mae_num = fmaf(w, fabsf(ov.z - hp), mae_num);
                hp = tv.w - iv.w; w = (fabsf(hp) > 0.0f) ? 1.0f : 0.0f;
                mae_den += w; mae_num = fmaf(w, fabsf(ov.w - hp), mae_num);
            }
        }
    }
    __syncthreads();                            // the ONLY barrier

    const int lane = tid & 63;
    const int g    = tid >> 6;                  // wave index, uniform
    const int rb   = g * 7;                     // first owned out row
    const int nrows = (g == 3) ? 6 : 7;

    // ---------------- Phase V: vertical conv, wave-local rows -------------
    {
        const int c     = lane;
        const int nread = (g == 3) ? 16 : 17;

        __half2 a01[7], a23[7];
        __half  a4[7];
#pragma unroll
        for (int i2 = 0; i2 < 7; ++i2) {
            a01[i2] = __half2half2(__float2half_rn(0.0f));
            a23[i2] = a01[i2];
            a4[i2]  = __float2half_rn(0.0f);
        }
#pragma unroll
        for (int ir = 0; ir < 17; ++ir) {
            if (ir < nread) {                   // wave-uniform
                const __half2 q  = xyt[rb + ir][c];
                const __half2 qq = __hmul2(q, q);
                const __half  xyh = __hmul(__low2half(q), __high2half(q));
#pragma unroll
                for (int i2 = 0; i2 < 7; ++i2) {
                    const int j = ir - i2;
                    if (j >= 0 && j <= 10) {    // folds at compile time
                        if (i2 < 6 || g < 3) {  // wave-uniform (i2==6 only)
                            a01[i2] = __hfma2(WH2[j], q,  a01[i2]);
                            a23[i2] = __hfma2(WH2[j], qq, a23[i2]);
                            a4[i2]  = __hfma(WH[j], xyh, a4[i2]);
                        }
                    }
                }
            }
        }
#pragma unroll
        for (int i2 = 0; i2 < 7; ++i2) {
            if (i2 < 6 || g < 3) {
                V01[rb + i2][c] = a01[i2];
                V23[rb + i2][c] = a23[i2];
                V4 [rb + i2][c] = a4[i2];
            }
        }
    }
    // NO BARRIER: wave g reads back only rows rb..rb+nrows-1, which this
    // same wave wrote; LDS ops are in-order within a wave (lgkmcnt).

    // ---------------- Phase H: wave-local horizontal conv + SSIM ----------
    // nrows x 9 groups (6 out cols) = 63 (54) units on 64 lanes.
    float ssim_acc = 0.0f;
    if (lane < nrows * 9) {
        const int row_l = lane / 9;
        const int grp   = lane - row_l * 9;
        const int row   = rb + row_l;
        const int c0    = grp * 6;              // 0,6,..,48

        __half2 w01[16], w23[16];
        __half  w4[16];
        {
            const __half2* r01 = &V01[row][c0];
            const __half2* r23 = &V23[row][c0];
            const __half*  r4  = &V4 [row][c0];
#pragma unroll
            for (int t = 0; t < 8; ++t) {       // 8B-aligned b64 reads
                const h2x2 qa = *(const h2x2*)(r01 + 2 * t);
                w01[2*t] = qa.a; w01[2*t+1] = qa.b;
                const h2x2 qb = *(const h2x2*)(r23 + 2 * t);
                w23[2*t] = qb.a; w23[2*t+1] = qb.b;
                const __half2 qc = *(const __half2*)(r4 + 2 * t); // b32
                w4[2*t] = __low2half(qc); w4[2*t+1] = __high2half(qc);
            }
        }
#pragma unroll
        for (int k = 0; k < 6; ++k) {
            __half2 s01 = __half2half2(__float2half_rn(0.0f));
            __half2 s23 = s01;
            __half  s4  = __float2half_rn(0.0f);
#pragma unroll
            for (int j = 0; j < 11; ++j) {
                s01 = __hfma2(WH2[j], w01[k + j], s01);
                s23 = __hfma2(WH2[j], w23[k + j], s23);
                s4  = __hfma(WH[j], w4[k + j], s4);
            }
            const float mu1 = __low2float(s01);
            const float mu2 = __high2float(s01);
            const float sxx = __low2float(s23);
            const float syy = __high2float(s23);
            const float sxy = __half2float(s4);
            const float mu1sq = mu1 * mu1;
            const float mu2sq = mu2 * mu2;
            const float mu12  = mu1 * mu2;
            const float num = (2.0f * mu12 + C1c) * (2.0f * (sxy - mu12) + C2c);
            const float den = (mu1sq + mu2sq + C1c) *
                              ((sxx - mu1sq) + (syy - mu2sq) + C2c);
            ssim_acc = fmaf(num, __builtin_amdgcn_rcpf(den), ssim_acc);
        }
    }

    // ---------------- Reduction -> slotted atomics ------------------------
    float v0 = mae_num, v1 = mae_den, v2 = ssim_acc;
#pragma unroll
    for (int off = 32; off >= 1; off >>= 1) {
        v0 += __shfl_down(v0, off);
        v1 += __shfl_down(v1, off);
        v2 += __shfl_down(v2, off);
    }
    if (lane == 0) { red[g][0] = v0; red[g][1] = v1; red[g][2] = v2; }
    __syncthreads();
    if (tid == 0) {
        float r0s = 0.f, r1s = 0.f, r2s = 0.f;
#pragma unroll
        for (int w = 0; w < 4; ++w) {
            r0s += red[w][0]; r1s += red[w][1]; r2s += red[w][2];
        }
        const int slot = orig & (NSLOT - 1);
        atomicAdd(&ws[slot * 3 + 0], r0s);
        atomicAdd(&ws[slot * 3 + 1], r1s);
        atomicAdd(&ws[slot * 3 + 2], r2s);
    }
}

__global__ void finalize_kernel(const float* __restrict__ ws, float* __restrict__ out) {
    if (threadIdx.x == 0 && blockIdx.x == 0) {
        float r0 = 0.f, r1 = 0.f, r2 = 0.f;
        for (int i = 0; i < NSLOT; ++i) {
            r0 += ws[i * 3 + 0];
            r1 += ws[i * 3 + 1];
            r2 += ws[i * 3 + 2];
        }
        const float mae = r0 / (r1 + 1e-8f);
        const float ssim_mean = r2 * (1.0f / 11943936.0f);  // 4096 * 54 * 54
        out[0] = 0.5f * mae + 0.5f * (1.0f - ssim_mean);
    }
}

extern "C" void kernel_launch(void* const* d_in, const int* in_sizes, int n_in,
                              void* d_out, int out_size, void* d_ws, size_t ws_size,
                              hipStream_t stream) {
    const float* in   = (const float*)d_in[0];
    const float* outp = (const float*)d_in[1];
    const float* tgt  = (const float*)d_in[2];
    float* ws = (float*)d_ws;

    hipMemsetAsync(d_ws, 0, NSLOT * 3 * sizeof(float), stream);
    fused_loss_kernel<<<8192, 256, 0, stream>>>(in, outp, tgt, ws);
    finalize_kernel<<<1, 64, 0, stream>>>(ws, (float*)d_out);
}